// Round 1
// baseline (200.047 us; speedup 1.0000x reference)
//
#include <hip/hip_runtime.h>

typedef unsigned short u16;
typedef unsigned int u32;
typedef __attribute__((ext_vector_type(8))) short short8;
typedef __attribute__((ext_vector_type(4))) float f32x4;

__device__ __forceinline__ u16 f2bf(float f) {
  union { float f; u32 u; } c; c.f = f;
  u32 u = c.u;
  u += 0x7fffu + ((u >> 16) & 1u);  // round-to-nearest-even
  return (u16)(u >> 16);
}
__device__ __forceinline__ float bf2f(u16 h) {
  union { u32 u; float f; } c; c.u = ((u32)h) << 16;
  return c.f;
}

// async global->LDS, 16B per lane; LDS layout must be linear in lane order
#define GLDS16(g, l)                                                          \
  __builtin_amdgcn_global_load_lds(                                           \
      (const __attribute__((address_space(1))) u32*)(g),                      \
      (__attribute__((address_space(3))) u32*)(l), 16, 0, 0)

// ---------------------------------------------------------------- cast x
__global__ __launch_bounds__(256) void k_cast_x(const float* __restrict__ x,
                                                u16* __restrict__ xb) {
  int i = blockIdx.x * 256 + threadIdx.x;
  float4 v = ((const float4*)x)[i];
  short4 s;
  s.x = (short)f2bf(v.x); s.y = (short)f2bf(v.y);
  s.z = (short)f2bf(v.z); s.w = (short)f2bf(v.w);
  *(short4*)(xb + (size_t)i * 4) = s;
}

// ------------------------------------------- transpose + cast weights (D=1024)
__global__ __launch_bounds__(256) void k_trans_w(
    const float* __restrict__ W0, const float* __restrict__ W1,
    const float* __restrict__ W2, const float* __restrict__ W3,
    u16* __restrict__ T0, u16* __restrict__ T1, u16* __restrict__ T2,
    u16* __restrict__ T3) {
  const float* W = blockIdx.z == 0 ? W0 : blockIdx.z == 1 ? W1 : blockIdx.z == 2 ? W2 : W3;
  u16* T = blockIdx.z == 0 ? T0 : blockIdx.z == 1 ? T1 : blockIdx.z == 2 ? T2 : T3;
  __shared__ float tile[32][33];
  int r0 = blockIdx.y * 32, c0 = blockIdx.x * 32;
  int tid = threadIdx.x;
  for (int i = tid; i < 1024; i += 256) {
    int r = i >> 5, c = i & 31;
    tile[r][c] = W[(size_t)(r0 + r) * 1024 + c0 + c];
  }
  __syncthreads();
  for (int i = tid; i < 1024; i += 256) {
    int r = i >> 5, c = i & 31;
    T[(size_t)(c0 + r) * 1024 + r0 + c] = f2bf(tile[c][r]);
  }
}

// ---------------------------------------------------------------- GEMM cores
// C[m,n] = sum_k A[m,k]*Bt[n,k]; A,Bt bf16 row-major, ld == K.
__device__ __forceinline__ void core128x128(const u16* __restrict__ A,
                                            const u16* __restrict__ Bt, int K,
                                            f32x4 (&acc)[4][4], u16* As, u16* Bs) {
  const int tid = threadIdx.x;
  const int lane = tid & 63;
  const int wm = tid >> 7, wn = (tid >> 6) & 1;
  const int fr = lane & 15, fg = lane >> 4;
#pragma unroll
  for (int i = 0; i < 4; ++i)
#pragma unroll
    for (int j = 0; j < 4; ++j) acc[i][j] = f32x4{0.f, 0.f, 0.f, 0.f};
  for (int kt = 0; kt < K; kt += 32) {
#pragma unroll
    for (int it = 0; it < 2; ++it) {
      int idx = it * 256 + tid;
      int row = idx >> 2, ch = (idx & 3) * 8;
      GLDS16(A + (size_t)row * K + kt + ch, As + idx * 8);
      GLDS16(Bt + (size_t)row * K + kt + ch, Bs + idx * 8);
    }
    __syncthreads();
    short8 af[4], bfv[4];
#pragma unroll
    for (int i = 0; i < 4; ++i)
      af[i] = *(const short8*)(As + (wm * 64 + i * 16 + fr) * 32 + fg * 8);
#pragma unroll
    for (int j = 0; j < 4; ++j)
      bfv[j] = *(const short8*)(Bs + (wn * 64 + j * 16 + fr) * 32 + fg * 8);
#pragma unroll
    for (int i = 0; i < 4; ++i)
#pragma unroll
      for (int j = 0; j < 4; ++j)
        acc[i][j] = __builtin_amdgcn_mfma_f32_16x16x32_bf16(af[i], bfv[j], acc[i][j], 0, 0, 0);
    __syncthreads();
  }
}

__device__ __forceinline__ void core128x64(const u16* __restrict__ A,
                                           const u16* __restrict__ Bt, int K,
                                           f32x4 (&acc)[2][4], u16* As, u16* Bs) {
  const int tid = threadIdx.x, lane = tid & 63, w = tid >> 6;
  const int fr = lane & 15, fg = lane >> 4;
#pragma unroll
  for (int i = 0; i < 2; ++i)
#pragma unroll
    for (int j = 0; j < 4; ++j) acc[i][j] = f32x4{0.f, 0.f, 0.f, 0.f};
  for (int kt = 0; kt < K; kt += 32) {
#pragma unroll
    for (int it = 0; it < 2; ++it) {
      int idx = it * 256 + tid;
      int row = idx >> 2, ch = (idx & 3) * 8;
      GLDS16(A + (size_t)row * K + kt + ch, As + idx * 8);
    }
    {
      int row = tid >> 2, ch = (tid & 3) * 8;
      GLDS16(Bt + (size_t)row * K + kt + ch, Bs + tid * 8);
    }
    __syncthreads();
    short8 af[2], bfv[4];
#pragma unroll
    for (int i = 0; i < 2; ++i)
      af[i] = *(const short8*)(As + (w * 32 + i * 16 + fr) * 32 + fg * 8);
#pragma unroll
    for (int j = 0; j < 4; ++j)
      bfv[j] = *(const short8*)(Bs + (j * 16 + fr) * 32 + fg * 8);
#pragma unroll
    for (int i = 0; i < 2; ++i)
#pragma unroll
      for (int j = 0; j < 4; ++j)
        acc[i][j] = __builtin_amdgcn_mfma_f32_16x16x32_bf16(af[i], bfv[j], acc[i][j], 0, 0, 0);
    __syncthreads();
  }
}

// ------------------------------------------------------- fused QKV projection
__global__ __launch_bounds__(256) void k_proj(
    const u16* __restrict__ xb, const u16* __restrict__ WqT,
    const u16* __restrict__ WkT, const u16* __restrict__ WvT,
    const float* __restrict__ bq, const float* __restrict__ bk,
    const float* __restrict__ bv, u16* __restrict__ qh, u16* __restrict__ kh,
    u16* __restrict__ vT) {
  __shared__ __align__(16) u16 As[128 * 32];
  __shared__ __align__(16) u16 Bs[128 * 32];
  const int which = blockIdx.z;
  const u16* Bt = which == 0 ? WqT : which == 1 ? WkT : WvT;
  const float* bias = which == 0 ? bq : which == 1 ? bk : bv;
  const int m0 = blockIdx.x * 128, n0 = blockIdx.y * 128;
  f32x4 acc[4][4];
  core128x128(xb + (size_t)m0 * 1024, Bt + (size_t)n0 * 1024, 1024, acc, As, Bs);
  const int tid = threadIdx.x, lane = tid & 63;
  const int wm = tid >> 7, wn = (tid >> 6) & 1, fr = lane & 15, fg = lane >> 4;
#pragma unroll
  for (int i = 0; i < 4; ++i)
#pragma unroll
    for (int j = 0; j < 4; ++j) {
      int n = n0 + wn * 64 + j * 16 + fr;
      float bb = bias[n];
      int h = n >> 6, dc = n & 63;
#pragma unroll
      for (int r = 0; r < 4; ++r) {
        int m = m0 + wm * 64 + i * 16 + fg * 4 + r;
        int b = m >> 10, nr = m & 1023;
        int z = b * 16 + h;
        float val = acc[i][j][r] + bb;
        if (which < 2) {
          u16* dst = which == 0 ? qh : kh;
          dst[((size_t)z * 1024 + nr) * 64 + dc] = f2bf(val);
        } else {
          vT[((size_t)z * 64 + dc) * 1024 + nr] = f2bf(val);
        }
      }
    }
}

// --------------------------------------------- fused scores + softmax -> att
// One block: 16 q-rows x full 1024 cols for one (b,h). 4 waves, each owns 16
// col-tiles (interleaved). K-tile LDS rows are 128B -> XOR-swizzle chunks.
__global__ __launch_bounds__(256) void k_scores(const u16* __restrict__ qh,
                                                const u16* __restrict__ kh,
                                                u16* __restrict__ att) {
  __shared__ __align__(16) u16 qs[16 * 64];
  __shared__ __align__(16) u16 ks[128 * 64];
  __shared__ __align__(16) u16 outs[16 * 1032];  // +8 pad vs 1024: spread banks
  __shared__ float red[4][16];
  const int z = blockIdx.y, m0 = blockIdx.x * 16;
  const int tid = threadIdx.x, lane = tid & 63, w = tid >> 6;
  const int fr = lane & 15, fg = lane >> 4;
  const u16* qb = qh + ((size_t)z * 1024 + m0) * 64;
  const u16* kb = kh + (size_t)z * 65536;
  if (tid < 128) {
    int row = tid >> 3, cc = tid & 7;
    GLDS16(qb + row * 64 + ((cc ^ (row & 7)) * 8), qs + tid * 8);
  }
  f32x4 acc[16];
#pragma unroll
  for (int t = 0; t < 16; ++t) acc[t] = f32x4{0.f, 0.f, 0.f, 0.f};
  for (int c = 0; c < 8; ++c) {
#pragma unroll
    for (int it = 0; it < 4; ++it) {
      int idx = it * 256 + tid;
      int row = idx >> 3, cc = idx & 7;
      GLDS16(kb + ((size_t)(c * 128 + row)) * 64 + ((cc ^ (row & 7)) * 8),
             ks + idx * 8);
    }
    __syncthreads();
    short8 aq0 = *(const short8*)(qs + fr * 64 + ((fg ^ (fr & 7)) * 8));
    short8 aq1 = *(const short8*)(qs + fr * 64 + (((4 + fg) ^ (fr & 7)) * 8));
#pragma unroll
    for (int s = 0; s < 2; ++s) {
      int ct = w + s * 4;
      int row = ct * 16 + fr;
      short8 b0 = *(const short8*)(ks + row * 64 + ((fg ^ (row & 7)) * 8));
      short8 b1 = *(const short8*)(ks + row * 64 + (((4 + fg) ^ (row & 7)) * 8));
      int t = c * 2 + s;
      acc[t] = __builtin_amdgcn_mfma_f32_16x16x32_bf16(aq0, b0, acc[t], 0, 0, 0);
      acc[t] = __builtin_amdgcn_mfma_f32_16x16x32_bf16(aq1, b1, acc[t], 0, 0, 0);
    }
    __syncthreads();
  }
  // ---- softmax (scale 1/8 folded into exp) ----
  float pm[4];
#pragma unroll
  for (int j = 0; j < 4; ++j) {
    float m = -3.0e38f;
#pragma unroll
    for (int t = 0; t < 16; ++t) m = fmaxf(m, acc[t][j]);
    pm[j] = m;
  }
#pragma unroll
  for (int off = 1; off < 16; off <<= 1)
#pragma unroll
    for (int j = 0; j < 4; ++j) pm[j] = fmaxf(pm[j], __shfl_xor(pm[j], off, 64));
  if (fr == 0) {
#pragma unroll
    for (int j = 0; j < 4; ++j) red[w][fg * 4 + j] = pm[j];
  }
  __syncthreads();
  float rm[4], ps[4];
#pragma unroll
  for (int j = 0; j < 4; ++j) {
    int rr = fg * 4 + j;
    rm[j] = fmaxf(fmaxf(red[0][rr], red[1][rr]), fmaxf(red[2][rr], red[3][rr]));
    ps[j] = 0.f;
  }
  __syncthreads();
#pragma unroll
  for (int t = 0; t < 16; ++t)
#pragma unroll
    for (int j = 0; j < 4; ++j) {
      float e = __expf((acc[t][j] - rm[j]) * 0.125f);
      acc[t][j] = e;
      ps[j] += e;
    }
#pragma unroll
  for (int off = 1; off < 16; off <<= 1)
#pragma unroll
    for (int j = 0; j < 4; ++j) ps[j] += __shfl_xor(ps[j], off, 64);
  if (fr == 0) {
#pragma unroll
    for (int j = 0; j < 4; ++j) red[w][fg * 4 + j] = ps[j];
  }
  __syncthreads();
  float inv[4];
#pragma unroll
  for (int j = 0; j < 4; ++j) {
    int rr = fg * 4 + j;
    inv[j] = 1.f / (red[0][rr] + red[1][rr] + red[2][rr] + red[3][rr]);
  }
#pragma unroll
  for (int t = 0; t < 16; ++t) {
    int gct = (t >> 1) * 8 + w + (t & 1) * 4;
    int col = gct * 16 + fr;
#pragma unroll
    for (int j = 0; j < 4; ++j)
      outs[(fg * 4 + j) * 1032 + col] = f2bf(acc[t][j] * inv[j]);
  }
  __syncthreads();
  u16* ob = att + ((size_t)z * 1024 + m0) * 1024;
  for (int idx = tid; idx < 2048; idx += 256) {
    int row = idx >> 7, cc = idx & 127;
    *(int4*)(ob + (size_t)row * 1024 + cc * 8) =
        *(const int4*)(outs + row * 1032 + cc * 8);
  }
}

// ----------------------------------------------------- P1 = att @ v  (-> P1T)
__global__ __launch_bounds__(256) void k_p1(const u16* __restrict__ att,
                                            const u16* __restrict__ vT,
                                            u16* __restrict__ P1T) {
  __shared__ __align__(16) u16 As[128 * 32];
  __shared__ __align__(16) u16 Bs[64 * 32];
  const int z = blockIdx.y, m0 = blockIdx.x * 128;
  f32x4 acc[2][4];
  core128x64(att + ((size_t)z * 1024 + m0) * 1024, vT + (size_t)z * 65536, 1024,
             acc, As, Bs);
  const int tid = threadIdx.x, lane = tid & 63, w = tid >> 6;
  const int fr = lane & 15, fg = lane >> 4;
  u16* pb = P1T + (size_t)z * 65536;
#pragma unroll
  for (int i = 0; i < 2; ++i)
#pragma unroll
    for (int j = 0; j < 4; ++j) {
      int cc = j * 16 + fr;
#pragma unroll
      for (int r = 0; r < 4; ++r) {
        int m = m0 + w * 32 + i * 16 + fg * 4 + r;
        pb[(size_t)cc * 1024 + m] = f2bf(acc[i][j][r]);
      }
    }
}

// ------------------- P2 = att @ P1, fused: OH = w0*v + (w1-wK)*P1 + 2*wK*P2
__global__ __launch_bounds__(256) void k_p2(
    const u16* __restrict__ att, const u16* __restrict__ P1T,
    const u16* __restrict__ vT, const float* __restrict__ w0,
    const float* __restrict__ w1, const float* __restrict__ wK,
    u16* __restrict__ OH) {
  __shared__ __align__(16) u16 As[128 * 32];
  __shared__ __align__(16) u16 Bs[64 * 32];
  const int z = blockIdx.y, m0 = blockIdx.x * 128;
  const int h = z & 15, b = z >> 4;
  f32x4 acc[2][4];
  core128x64(att + ((size_t)z * 1024 + m0) * 1024, P1T + (size_t)z * 65536,
             1024, acc, As, Bs);
  const int tid = threadIdx.x, lane = tid & 63, w = tid >> 6;
  const int fr = lane & 15, fg = lane >> 4;
  const float c1 = w1[h] - wK[h], c2 = 2.f * wK[h], c0 = w0[h];
  const u16* pb = P1T + (size_t)z * 65536;
  const u16* vb = vT + (size_t)z * 65536;
#pragma unroll
  for (int i = 0; i < 2; ++i)
#pragma unroll
    for (int j = 0; j < 4; ++j) {
      int cc = j * 16 + fr;
#pragma unroll
      for (int r = 0; r < 4; ++r) {
        int m = m0 + w * 32 + i * 16 + fg * 4 + r;
        float val = c2 * acc[i][j][r] + c1 * bf2f(pb[(size_t)cc * 1024 + m]) +
                    c0 * bf2f(vb[(size_t)cc * 1024 + m]);
        OH[((size_t)b * 1024 + m) * 1024 + h * 64 + cc] = f2bf(val);
      }
    }
}

// ------------------------------------------------- final: out = OH @ Wo + bo
__global__ __launch_bounds__(256) void k_final(const u16* __restrict__ OH,
                                               const u16* __restrict__ WoT,
                                               const float* __restrict__ bo,
                                               float* __restrict__ out) {
  __shared__ __align__(16) u16 As[128 * 32];
  __shared__ __align__(16) u16 Bs[128 * 32];
  const int m0 = blockIdx.x * 128, n0 = blockIdx.y * 128;
  f32x4 acc[4][4];
  core128x128(OH + (size_t)m0 * 1024, WoT + (size_t)n0 * 1024, 1024, acc, As, Bs);
  const int tid = threadIdx.x, lane = tid & 63;
  const int wm = tid >> 7, wn = (tid >> 6) & 1, fr = lane & 15, fg = lane >> 4;
#pragma unroll
  for (int i = 0; i < 4; ++i)
#pragma unroll
    for (int j = 0; j < 4; ++j) {
      int n = n0 + wn * 64 + j * 16 + fr;
      float bb = bo[n];
#pragma unroll
      for (int r = 0; r < 4; ++r) {
        int m = m0 + wm * 64 + i * 16 + fg * 4 + r;
        out[(size_t)m * 1024 + n] = acc[i][j][r] + bb;
      }
    }
}

extern "C" void kernel_launch(void* const* d_in, const int* in_sizes, int n_in,
                              void* d_out, int out_size, void* d_ws,
                              size_t ws_size, hipStream_t stream) {
  const float* x = (const float*)d_in[0];
  const float* Wq = (const float*)d_in[1];
  const float* bq = (const float*)d_in[2];
  const float* Wk = (const float*)d_in[3];
  const float* bk = (const float*)d_in[4];
  const float* Wv = (const float*)d_in[5];
  const float* bv = (const float*)d_in[6];
  const float* Wo = (const float*)d_in[7];
  const float* bo = (const float*)d_in[8];
  const float* w0 = (const float*)d_in[9];
  const float* w1 = (const float*)d_in[10];
  const float* wK = (const float*)d_in[11];
  float* out = (float*)d_out;

  char* ws = (char*)d_ws;
  const size_t MB = 1ull << 20;
  u16* xb  = (u16*)(ws);            // 8 MiB
  u16* WqT = (u16*)(ws + 8 * MB);   // 2 MiB
  u16* WkT = (u16*)(ws + 10 * MB);  // 2 MiB
  u16* WvT = (u16*)(ws + 12 * MB);  // 2 MiB
  u16* WoT = (u16*)(ws + 14 * MB);  // 2 MiB
  u16* qh  = (u16*)(ws + 16 * MB);  // 8 MiB  [B,H,N,d]
  u16* kh  = (u16*)(ws + 24 * MB);  // 8 MiB  [B,H,N,d]
  u16* vT  = (u16*)(ws + 32 * MB);  // 8 MiB  [B,H,d,N]
  u16* P1T = (u16*)(ws + 40 * MB);  // 8 MiB  [B,H,d,N]
  u16* OH  = (u16*)(ws + 48 * MB);  // 8 MiB  [B,N,D]
  u16* att = (u16*)(ws + 56 * MB);  // 128 MiB [B,H,N,N]

  hipLaunchKernelGGL(k_cast_x, dim3(4096), dim3(256), 0, stream, x, xb);
  hipLaunchKernelGGL(k_trans_w, dim3(32, 32, 4), dim3(256), 0, stream, Wq, Wk,
                     Wv, Wo, WqT, WkT, WvT, WoT);
  hipLaunchKernelGGL(k_proj, dim3(32, 8, 3), dim3(256), 0, stream, xb, WqT, WkT,
                     WvT, bq, bk, bv, qh, kh, vT);
  hipLaunchKernelGGL(k_scores, dim3(64, 64), dim3(256), 0, stream, qh, kh, att);
  hipLaunchKernelGGL(k_p1, dim3(8, 64), dim3(256), 0, stream, att, vT, P1T);
  hipLaunchKernelGGL(k_p2, dim3(8, 64), dim3(256), 0, stream, att, P1T, vT, w0,
                     w1, wK, OH);
  hipLaunchKernelGGL(k_final, dim3(32, 8), dim3(256), 0, stream, OH, WoT, bo,
                     out);
}